// Round 9
// baseline (372.328 us; speedup 1.0000x reference)
//
#include <hip/hip_runtime.h>
#include <stdint.h>

// HOPELoRALayer — B=8, S=4096, D=1024, R_TOT=104. fp32 I/O; bf16 MFMA GEMM.
// Reductions:
//   gate_scale = mean(softmax over 3) == 1/3 exactly -> gate net dead code.
//   out = X @ (base_w + (1/3) pu@diag(1+mem)@pd)^T + base_b
// mem==0 (fresh state) -> batch-independent W0; general case via flags+Weff.
//
// R12 change: OCCUPANCY. R4..R11 schedule variants all null because 256² tile
// = 220 regs/wave x 8 waves -> 1 block/CU, 2 waves/SIMD (Occupancy ~21%) —
// barrier-locked pairs can't overlap anything. New geometry: 128x128 tile,
// 4 waves x 64x64 (acc=64 VGPR), 3-deep LDS ring 48KB -> 3 blocks/CU
// (12 waves/CU), the m97/912TF regime where independent blocks hide stalls.
// Ring proof: iter kt reads buf[kt%3], writes buf[(kt+2)%3] (never equal);
// 1 barrier/iter bounds skew to intra-iter -> race-free. Waits: A_WRITE(kt+2)
// implicit counted vmcnt drains {B(kt+1), A(kt+2)} each iter (B older than A
// by issue order); prologue [B0:2,B1:2,A2:4] -> vmcnt(6); B(31) drained by
// explicit vmcnt(0) at kt==30. Fused A-path kept (saves ~49us residual).
// Also: prep grid 9216 -> 2304 blocks (512-thr, 4 rows) — dispatch-cost probe.

typedef unsigned short ushort_t;
typedef unsigned short us8 __attribute__((ext_vector_type(8)));
typedef short short8 __attribute__((ext_vector_type(8)));
typedef float f32x4 __attribute__((ext_vector_type(4)));

__device__ __forceinline__ ushort_t f2b(float f) {  // RNE fp32->bf16
  union { float f; uint32_t i; } v; v.f = f;
  uint32_t lsb = (v.i >> 16) & 1u;
  v.i += 0x7fffu + lsb;
  return (ushort_t)(v.i >> 16);
}

__device__ __forceinline__ void async16(const void* g, void* l) {
  __builtin_amdgcn_global_load_lds(
      (const __attribute__((address_space(1))) void*)g,
      (__attribute__((address_space(3))) void*)l, 16, 0, 0);
}

// ---- merged prep: y==0 -> W0 rows; y=1..8 -> flags[b] + Weff rows if mem!=0
// 512-thread blocks, 4 output rows each: grid (256, 9) = 2304 blocks.
__global__ __launch_bounds__(512) void prep(const float* __restrict__ base_w,
                                            const float* __restrict__ pu_w,
                                            const float* __restrict__ pd_w,
                                            const float* __restrict__ mf,
                                            const float* __restrict__ mm,
                                            const float* __restrict__ ms,
                                            ushort_t* __restrict__ W0,
                                            ushort_t* __restrict__ Weff,
                                            int* __restrict__ flags) {
  const int y = blockIdx.y, t = threadIdx.x;
  const int rg = t >> 7, tl = t & 127;          // row-group 0..3, lane-in-row
  const int o = blockIdx.x * 4 + rg;            // output row 0..1023
  __shared__ float spu[4][104];
  __shared__ int sflag;
  ushort_t* dst;

  if (y == 0) {
    if (tl < 104) spu[rg][tl] = pu_w[o * 104 + tl] * (1.0f / 3.0f);
    dst = W0 + o * 1024;
    __syncthreads();
  } else {
    const int b = y - 1;
    if (t == 0) sflag = 0;
    __syncthreads();
    float mv = 0.0f;
    if (tl < 104) {
      mv = (tl < 8) ? mf[b * 8 + tl]
         : (tl < 40) ? mm[b * 32 + (tl - 8)]
                     : ms[b * 64 + (tl - 40)];
      if (mv != 0.0f) sflag = 1;
      spu[rg][tl] = pu_w[o * 104 + tl] * (1.0f + mv) * (1.0f / 3.0f);
    }
    __syncthreads();
    if (blockIdx.x == 0 && t == 0) flags[b] = sflag;
    if (!sflag) return;  // block-uniform
    dst = Weff + ((size_t)b << 20) + o * 1024;
  }

  const int d0 = tl * 8;
  float acc[8];
  f32x4 b0 = *(const f32x4*)(base_w + o * 1024 + d0);
  f32x4 b1 = *(const f32x4*)(base_w + o * 1024 + d0 + 4);
#pragma unroll
  for (int j = 0; j < 4; j++) { acc[j] = b0[j]; acc[4 + j] = b1[j]; }
  for (int r = 0; r < 104; r++) {
    f32x4 p0 = *(const f32x4*)(pd_w + r * 1024 + d0);
    f32x4 p1 = *(const f32x4*)(pd_w + r * 1024 + d0 + 4);
    float s = spu[rg][r];
#pragma unroll
    for (int j = 0; j < 4; j++) { acc[j] += s * p0[j]; acc[4 + j] += s * p1[j]; }
  }
  us8 ov;
#pragma unroll
  for (int j = 0; j < 8; j++) ov[j] = f2b(acc[j]);
  *(us8*)(dst + d0) = ov;
}

// ---- main GEMM: out[b, m, n] = sum_k x[b,m,k] * W[n,k] + base_b[n] --------
// 128x128 tile, BK=32. 4 waves (2x2), per-wave 64x64 out = 4x4 frags of
// mfma_f32_16x16x32_bf16. Grid 2048: b = flat&7 (batch==XCD), bn-inner.
// A fused from fp32 x (reg-stage + RNE cvt + swizzled ds_write, issue 3 ahead).
__global__ __launch_bounds__(256, 3) void gemm128(
    const float* __restrict__ x, const float* __restrict__ base_b,
    const ushort_t* __restrict__ W0, const ushort_t* __restrict__ Weff,
    const int* __restrict__ flags, float* __restrict__ out) {
  const int flat = blockIdx.x;
  const int b  = flat & 7;                 // batch == XCD
  const int i  = flat >> 3;                // 0..255
  const int bm = i >> 3;                   // 0..31 (M tile)
  const int bn = i & 7;                    // 0..7  (N tile) — A-panel L2 reuse

  const ushort_t* W = flags[b] ? (Weff + ((size_t)b << 20)) : W0;

  // 3-deep ring: per buffer A[128][32] (8KiB) + B[128][32] (8KiB) = 16KiB
  __shared__ __align__(16) char lds[3 * 16384];  // 48 KiB -> 3 blocks/CU

  const int t = threadIdx.x;
  const int w = t >> 6, l = t & 63;
  const int wr = w >> 1, wc = w & 1;       // wave -> 64x64 quadrant
  const int row16 = l & 15, quad = l >> 4;

  // ---- B staging (global_load_lds, source carries the inverse swizzle) ----
  const int srow = w * 16 + (l >> 2);                  // rows [w*16, w*16+16)
  const int scol = ((l & 3) ^ ((srow >> 1) & 3)) * 8;  // bf16 units
  const ushort_t* gB = W + (((size_t)(bn * 128 + srow)) << 10) + scol;

  // ---- A staging (reg-staged fp32 -> cvt -> swizzled ds_write) ----
  // thread t covers LDS row ar = t>>1 (0..127), fp32 cols (t&1)*16..+16.
  const int ar = t >> 1;
  const int ac = (t & 1) * 16;
  const float* gA = x + (((size_t)b * 4096 + bm * 128 + ar) << 10) + ac;
  const int fr_ = (ar >> 1) & 3;                       // row swizzle key
  const int ws0 = (((t & 1) * 2 + 0) ^ fr_) * 16;      // byte slots
  const int ws1 = (((t & 1) * 2 + 1) ^ fr_) * 16;

  // ---- ds_read addressing (same XOR on the k-slot) ----
  const int qsw = (quad ^ ((row16 >> 1) & 3)) * 16;          // byte slot
  const int aoff = (wr * 64 + row16) * 64 + qsw;             // + mi*1024
  const int boff = 8192 + (wc * 64 + row16) * 64 + qsw;      // + ni*1024

#define STAGE_B(kt2)                                                      \
  {                                                                       \
    const ushort_t* g_ = gB + (kt2) * 32;                                 \
    char* d_ = lds + ((kt2) % 3) * 16384 + 8192 + w * 1024;               \
    async16(g_, d_);                                                      \
    async16(g_ + (64 << 10), d_ + 4096);                                  \
  }
#define A_ISSUE(kt2)                                                      \
  {                                                                       \
    const float* p_ = gA + (kt2) * 32;                                    \
    s0 = *(const f32x4*)(p_);      s1 = *(const f32x4*)(p_ + 4);          \
    s2 = *(const f32x4*)(p_ + 8);  s3 = *(const f32x4*)(p_ + 12);         \
  }
#define A_WRITE(kt2)                                                      \
  {                                                                       \
    us8 o0, o1;                                                           \
    _Pragma("unroll")                                                     \
    for (int j_ = 0; j_ < 4; ++j_) {                                      \
      o0[j_] = f2b(s0[j_]); o0[4 + j_] = f2b(s1[j_]);                     \
      o1[j_] = f2b(s2[j_]); o1[4 + j_] = f2b(s3[j_]);                     \
    }                                                                     \
    char* d_ = lds + ((kt2) % 3) * 16384 + ar * 64;                       \
    *(us8*)(d_ + ws0) = o0;                                               \
    *(us8*)(d_ + ws1) = o1;                                               \
  }

  f32x4 acc[4][4] = {};
  f32x4 s0, s1, s2, s3;

  // prologue. Order matters for the counted waits: B1 issued BEFORE A2 so the
  // steady-state invariant (B(kt+1) older than A(kt+2)) holds from iter 0.
  // Queue at final wait: [B0:2, B1:2, A2:4] -> vmcnt(6) drains exactly B0.
  A_ISSUE(0) A_WRITE(0)            // buf0 (implicit full drain of A0 — prologue only)
  A_ISSUE(1) STAGE_B(0)            // [A1:4, B0:2]
  A_WRITE(1)                       // vmcnt(2): drains A1, leaves B0; buf1
  STAGE_B(1) A_ISSUE(2)            // [B0:2, B1:2, A2:4]
  asm volatile("s_waitcnt vmcnt(6) lgkmcnt(0)" ::: "memory");
  __builtin_amdgcn_s_barrier();

  for (int kt = 0; kt < 32; ++kt) {
    const char* cur = lds + (kt % 3) * 16384;

    // ---- staging group (pinned before compute). A_WRITE(kt+2)'s implicit
    // counted vmcnt drains {B(kt+1), A(kt+2)} (both issued last iter, older
    // than the just-issued B(kt+2)); leaves {B(kt+2), A(kt+3)} in flight.
    if (kt <= 29) { STAGE_B(kt + 2) A_WRITE(kt + 2) }
    if (kt <= 28) A_ISSUE(kt + 3)
    __builtin_amdgcn_sched_barrier(0);

    // ---- compute: 8 ds_read_b128 + 16 MFMA, compiler-interleaved ----
    __builtin_amdgcn_s_setprio(1);
    short8 af[4], bf[4];
#pragma unroll
    for (int mi = 0; mi < 4; ++mi)
      af[mi] = *(const short8*)(cur + aoff + mi * 1024);
#pragma unroll
    for (int ni = 0; ni < 4; ++ni)
      bf[ni] = *(const short8*)(cur + boff + ni * 1024);
#pragma unroll
    for (int mi = 0; mi < 4; ++mi)
#pragma unroll
      for (int ni = 0; ni < 4; ++ni)
        acc[mi][ni] = __builtin_amdgcn_mfma_f32_16x16x32_bf16(af[mi], bf[ni],
                                                              acc[mi][ni], 0, 0, 0);
    __builtin_amdgcn_s_setprio(0);

    // ---- iter end: kt==30 must drain B(31) (no A_WRITE covers it).
    // lgkm(0) publishes this iter's ds_writes; ONE barrier per iter.
    if (kt == 30) asm volatile("s_waitcnt vmcnt(0)" ::: "memory");
    asm volatile("s_waitcnt lgkmcnt(0)" ::: "memory");
    __builtin_amdgcn_sched_barrier(0);
    __builtin_amdgcn_s_barrier();
  }

  // epilogue: C/D layout col=lane&15, row=quad*4+reg (m89-verified)
#pragma unroll
  for (int ni = 0; ni < 4; ++ni) {
    const int col = bn * 128 + wc * 64 + ni * 16 + row16;
    const float bb = base_b[col];
#pragma unroll
    for (int mi = 0; mi < 4; ++mi) {
      const int row = bm * 128 + wr * 64 + mi * 16 + quad * 4;
      float* po = out + (((size_t)b * 4096 + row) << 10) + col;
#pragma unroll
      for (int i2 = 0; i2 < 4; ++i2)
        po[(size_t)i2 << 10] = acc[mi][ni][i2] + bb;
    }
  }
#undef STAGE_B
#undef A_ISSUE
#undef A_WRITE
}

extern "C" void kernel_launch(void* const* d_in, const int* in_sizes, int n_in,
                              void* d_out, int out_size, void* d_ws, size_t ws_size,
                              hipStream_t stream) {
  const float* x  = (const float*)d_in[0];
  const float* mf = (const float*)d_in[1];
  const float* mm = (const float*)d_in[2];
  const float* ms = (const float*)d_in[3];
  const float* base_w = (const float*)d_in[4];
  const float* base_b = (const float*)d_in[5];
  const float* pd_w = (const float*)d_in[6];
  const float* pu_w = (const float*)d_in[7];
  // d_in[8..11] (gate net) are mathematically dead: mean(softmax_3) == 1/3.

  char* ws = (char*)d_ws;
  int* flags     = (int*)ws;                                   // 32 B
  ushort_t* W0   = (ushort_t*)(ws + 4096);                     // 2 MiB
  ushort_t* Weff = (ushort_t*)(ws + 4096 + (2u << 20));        // 16 MiB, cold

  prep<<<dim3(256, 9), 512, 0, stream>>>(base_w, pu_w, pd_w, mf, mm, ms,
                                         W0, Weff, flags);
  gemm128<<<2048, 256, 0, stream>>>(x, base_b, W0, Weff, flags, (float*)d_out);
}